// Round 2
// baseline (462.615 us; speedup 1.0000x reference)
//
#include <hip/hip_runtime.h>
#include <hip/hip_bf16.h>

typedef __hip_bfloat16 bf16;
typedef unsigned short u16;
typedef __attribute__((ext_vector_type(8))) short short8;
typedef __attribute__((ext_vector_type(4))) short s4v;
typedef __attribute__((ext_vector_type(4))) float f32x4;
typedef __attribute__((ext_vector_type(4))) unsigned int u32x4;

#define LEAK 0.1f
#define EPS_ 1e-5f
#define MFMA(a, b, c) __builtin_amdgcn_mfma_f32_16x16x32_bf16(a, b, c, 0, 0, 0)
// N=32 C=64 T=400 V=27 S=2 IC=16 O=64; P = T*V = 10800 per n.

__device__ __forceinline__ float u2f(u16 u) { return __uint_as_float(((unsigned int)u) << 16); }
__device__ __forceinline__ u16 f2u(float f) {
  bf16 h = __float2bfloat16(f);
  u16 r;
  __builtin_memcpy(&r, &h, 2);
  return r;
}
__device__ __forceinline__ f32x4 z4() { f32x4 z = {0.f, 0.f, 0.f, 0.f}; return z; }

// ---------------------------------------------------------------------------
// G1: qk = W_in @ (x+pe) + b_in over the full P dimension.
// Block = (n, 256-p chunk). Staging threads assemble exact pre-fragmented
// 16B B-frag slots in LDS (one barrier); compute is conflict-free b128 reads.
// Output written TRANSPOSED for the logit kernel: qG/kG[n][s][u(pad32)][t*16+i].
// ---------------------------------------------------------------------------
__global__ __launch_bounds__(256) void g_qk(
    const float* __restrict__ x, const float* __restrict__ pe,
    const float* __restrict__ W_in, const float* __restrict__ b_in,
    u16* __restrict__ qG, u16* __restrict__ kG)
{
  __shared__ u32x4 sB[16][2][64];  // [p-tile][kf][lane] pre-fragmented B
  const int tid = threadIdx.x;
  const int w = tid >> 6, lane = tid & 63;
  const int m = lane & 15, quad = lane >> 4;
  const int n = blockIdx.y, p0 = blockIdx.x * 256;

  // persistent W_in A-frags (rows r = 16w+m)  [verified pattern]
  short8 aW[2];
#pragma unroll
  for (int kf = 0; kf < 2; ++kf) {
    short8 tt;
#pragma unroll
    for (int j = 0; j < 8; ++j)
      tt[j] = (short)f2u(W_in[(16 * w + m) * 64 + 32 * kf + 8 * quad + j]);
    aW[kf] = tt;
  }
  float bb[4];
#pragma unroll
  for (int r = 0; r < 4; ++r) bb[r] = b_in[16 * w + quad * 4 + r];

  // stage: thread builds 8 slots; global reads 64B-coalesced along p
#pragma unroll
  for (int k = 0; k < 8; ++k) {
    int slot = tid + 256 * k;
    int tile = slot >> 7, kf = (slot >> 6) & 1;
    int qq = (slot >> 4) & 3, mm = slot & 15;
    int p = p0 + tile * 16 + mm;
    int c0 = kf * 32 + qq * 8;
    short8 tt = {0, 0, 0, 0, 0, 0, 0, 0};
    if (p < 10800) {
#pragma unroll
      for (int j = 0; j < 8; ++j)
        tt[j] = (short)f2u(x[(n * 64 + c0 + j) * 10800 + p] +
                           pe[(c0 + j) * 10800 + p]);
    }
    *(short8*)&sB[tile][kf][slot & 63] = tt;
  }
  __syncthreads();

  // wave w: rows 16w..16w+15.  w0,w1 -> q (s=0,1); w2,w3 -> k (s=0,1)
  u16* dst = (w < 2 ? qG : kG) + (n * 2 + (w & 1)) * 32 * 6400;
#pragma unroll 4
  for (int tile = 0; tile < 16; ++tile) {
    short8 b0 = *(const short8*)&sB[tile][0][lane];
    short8 b1 = *(const short8*)&sB[tile][1][lane];
    f32x4 acc = MFMA(aW[0], b0, z4());
    acc = MFMA(aW[1], b1, acc);
    int p = p0 + tile * 16 + m;
    if (p < 10800) {
      unsigned t = (unsigned)p / 27u;
      unsigned u = (unsigned)p - 27u * t;
      s4v pk;
#pragma unroll
      for (int reg = 0; reg < 4; ++reg) pk[reg] = (short)f2u(acc[reg] + bb[reg]);
      *(s4v*)&dst[(u * 400 + t) * 16 + quad * 4] = pk;  // i = 4*quad+reg run
    }
  }
}

// ---------------------------------------------------------------------------
// G2: att[n,s,u,v] = tanh( (q.k over (i,t)) / 6400 ) * alphas[s] + att0.
// Block = (s, n); 4 waves split K=6400; direct-global frag loads (64B
// coalesced across quads); LDS reduce + fused finalize. No atomics.
// ---------------------------------------------------------------------------
__global__ __launch_bounds__(256) void g_att(
    const u16* __restrict__ qG, const u16* __restrict__ kG,
    const float* __restrict__ alphas, const float* __restrict__ att0,
    float* __restrict__ att)
{
  __shared__ float sred[4][64][16];
  const int tid = threadIdx.x;
  const int w = tid >> 6, lane = tid & 63;
  const int m = lane & 15, quad = lane >> 4;
  const int s = blockIdx.x, n = blockIdx.y;
  const u16* qb = qG + (n * 2 + s) * 32 * 6400;
  const u16* kb = kG + (n * 2 + s) * 32 * 6400;

  f32x4 a00 = z4(), a01 = z4(), a10 = z4(), a11 = z4();
#pragma unroll 2
  for (int it = 0; it < 25; ++it) {
    int kk0 = w * 1600 + it * 64;
#pragma unroll
    for (int kf = 0; kf < 2; ++kf) {
      int kk = kk0 + kf * 32 + quad * 8;
      short8 aq0 = *(const short8*)&qb[m * 6400 + kk];
      short8 aq1 = *(const short8*)&qb[(16 + m) * 6400 + kk];
      short8 bk0 = *(const short8*)&kb[m * 6400 + kk];
      short8 bk1 = *(const short8*)&kb[(16 + m) * 6400 + kk];
      a00 = MFMA(aq0, bk0, a00);
      a01 = MFMA(aq0, bk1, a01);
      a10 = MFMA(aq1, bk0, a10);
      a11 = MFMA(aq1, bk1, a11);
    }
  }
  *(f32x4*)&sred[w][lane][0] = a00;
  *(f32x4*)&sred[w][lane][4] = a01;
  *(f32x4*)&sred[w][lane][8] = a10;
  *(f32x4*)&sred[w][lane][12] = a11;
  __syncthreads();
  const float al = alphas[s];
#pragma unroll
  for (int k = 0; k < 4; ++k) {
    int slot = tid + 256 * k;
    int lsrc = slot >> 4, idx = slot & 15;
    float val = sred[0][lsrc][idx] + sred[1][lsrc][idx] +
                sred[2][lsrc][idx] + sred[3][lsrc][idx];
    int f = idx >> 2, reg = idx & 3;
    int ut = f >> 1, vt = f & 1;
    int qq = lsrc >> 4, mm = lsrc & 15;
    int u = ut * 16 + qq * 4 + reg, v = vt * 16 + mm;
    if (u < 27 && v < 27)
      att[(n * 2 + s) * 729 + u * 27 + v] =
          tanhf(val * (1.f / 6400.f)) * al + att0[s * 729 + u * 27 + v];
  }
}

// ---------------------------------------------------------------------------
// G3 (y2+y3 fused): block = (n, 4 t-slices).
// Phase1: y2 = x . att  -> pre-fragmented LDS slots (b64 half-slot writes).
// ONE barrier. Phase2: y3 = lrelu(x + bn(W_out@y2)) -> y3T[n*10800+p][o64].
// ---------------------------------------------------------------------------
__global__ __launch_bounds__(256) void g_ab(
    const float* __restrict__ x, const float* __restrict__ att,
    const float* __restrict__ W_out, const float* __restrict__ b_out,
    const float* __restrict__ g_out, const float* __restrict__ be_out,
    const float* __restrict__ m_out, const float* __restrict__ v_out,
    u16* __restrict__ y3T)
{
  __shared__ u32x4 sy2f[4][2][4][64];  // [t][vt][kf][lane]
  const int tid = threadIdx.x;
  const int w = tid >> 6, lane = tid & 63;
  const int m = lane & 15, quad = lane >> 4;
  const int n = blockIdx.y, t0 = blockIdx.x * 4;

  // att B-frags  [verified pattern]
  short8 bAtt[4];
#pragma unroll
  for (int s = 0; s < 2; ++s)
#pragma unroll
    for (int nt = 0; nt < 2; ++nt) {
      short8 tt;
#pragma unroll
      for (int j = 0; j < 8; ++j) {
        int u = 8 * quad + j, v = 16 * nt + m;
        tt[j] = (u < 27 && v < 27) ? (short)f2u(att[(n * 2 + s) * 729 + u * 27 + v]) : (short)0;
      }
      bAtt[s * 2 + nt] = tt;
    }
  // W_out A-frags + BN consts  [verified patterns]
  short8 aWo[4];
#pragma unroll
  for (int kf = 0; kf < 4; ++kf) {
    short8 tt;
#pragma unroll
    for (int j = 0; j < 8; ++j)
      tt[j] = (short)f2u(W_out[(16 * w + m) * 128 + 32 * kf + 8 * quad + j]);
    aWo[kf] = tt;
  }
  float Ao[4], Bo[4];
#pragma unroll
  for (int reg = 0; reg < 4; ++reg) {
    int o = 16 * w + quad * 4 + reg;
    float sc = g_out[o] * rsqrtf(v_out[o] + EPS_);
    Ao[reg] = sc;
    Bo[reg] = (b_out[o] - m_out[o]) * sc + be_out[o];
  }

  const int q1 = quad & 1;
  const int qp = (2 * w + (quad >> 1)) & 3;
  // phase 1: y2 frags for 4 slices
#pragma unroll
  for (int tc = 0; tc < 4; ++tc) {
    int t = t0 + tc;
    short8 ax;
#pragma unroll
    for (int j = 0; j < 8; ++j) {
      int u = quad * 8 + j;
      ax[j] = (u < 27) ? (short)f2u(x[((n * 64 + 16 * w + m) * 400 + t) * 27 + u]) : (short)0;
    }
    f32x4 acc[4];
#pragma unroll
    for (int f = 0; f < 4; ++f) acc[f] = MFMA(ax, bAtt[f], z4());
#pragma unroll
    for (int s = 0; s < 2; ++s)
#pragma unroll
      for (int nt = 0; nt < 2; ++nt) {
        f32x4 a = acc[s * 2 + nt];
        s4v pk;
#pragma unroll
        for (int reg = 0; reg < 4; ++reg) pk[reg] = (short)f2u(a[reg]);
        int kfp = 2 * s + (w >> 1);
        *(s4v*)((u16*)&sy2f[tc][nt][kfp][qp * 16 + m] + 4 * q1) = pk;
      }
  }
  __syncthreads();
  // phase 2: y3
#pragma unroll
  for (int tc = 0; tc < 4; ++tc) {
    int t = t0 + tc;
#pragma unroll
    for (int vt = 0; vt < 2; ++vt) {
      f32x4 a0 = z4();
#pragma unroll
      for (int kf = 0; kf < 4; ++kf) {
        short8 b = *(const short8*)&sy2f[tc][vt][kf][lane];
        a0 = MFMA(aWo[kf], b, a0);
      }
      int v = vt * 16 + m;
      if (v < 27) {
        s4v pk;
#pragma unroll
        for (int reg = 0; reg < 4; ++reg) {
          int o = 16 * w + quad * 4 + reg;
          float r = x[((n * 64 + o) * 400 + t) * 27 + v] + a0[reg] * Ao[reg] + Bo[reg];
          pk[reg] = (short)f2u((r >= 0.f) ? r : LEAK * r);
        }
        *(s4v*)&y3T[(unsigned)(n * 10800 + t * 27 + v) * 64 + 16 * w + quad * 4] = pk;
      }
    }
  }
}

// ---------------------------------------------------------------------------
// G4 (y4+z fused): block = (n, 4 t + halo).
// Phase1: y4 = lrelu(x + bn(W_ff@y3)) for 6 slices -> pre-frag LDS;
// residual y4 (center slices) kept in f32 regs. ONE barrier.
// Phase2: z = lrelu(y4 + bn(conv3(y4))) -> out (f32, coalesced).
// ---------------------------------------------------------------------------
__global__ __launch_bounds__(256) void g_cd(
    const float* __restrict__ x, const u16* __restrict__ y3T,
    const float* __restrict__ W_ff, const float* __restrict__ b_ff,
    const float* __restrict__ g_ff, const float* __restrict__ be_ff,
    const float* __restrict__ m_ff, const float* __restrict__ v_ff,
    const float* __restrict__ W_t, const float* __restrict__ b_t,
    const float* __restrict__ g_t, const float* __restrict__ be_t,
    const float* __restrict__ m_t, const float* __restrict__ v_t,
    float* __restrict__ out)
{
  __shared__ u32x4 sy4f[6][2][2][64];  // [tl][vt][ihalf][lane]
  const int tid = threadIdx.x;
  const int w = tid >> 6, lane = tid & 63;
  const int m = lane & 15, quad = lane >> 4;
  const int n = blockIdx.y, t0 = blockIdx.x * 4;

  short8 aWf[2], aWt[6];
#pragma unroll
  for (int kf = 0; kf < 2; ++kf) {
    short8 tt;
#pragma unroll
    for (int j = 0; j < 8; ++j)
      tt[j] = (short)f2u(W_ff[(16 * w + m) * 64 + 32 * kf + 8 * quad + j]);
    aWf[kf] = tt;
  }
#pragma unroll
  for (int kf = 0; kf < 6; ++kf) {  // k = dt*64 + i   [verified pattern]
    short8 tt;
    int dt = kf >> 1;
#pragma unroll
    for (int j = 0; j < 8; ++j) {
      int ii = 32 * (kf & 1) + 8 * quad + j;
      tt[j] = (short)f2u(W_t[((16 * w + m) * 64 + ii) * 3 + dt]);
    }
    aWt[kf] = tt;
  }
  float Af[4], Bf[4], At[4], Bt[4];
#pragma unroll
  for (int reg = 0; reg < 4; ++reg) {
    int o = 16 * w + quad * 4 + reg;
    float sc;
    sc = g_ff[o] * rsqrtf(v_ff[o] + EPS_); Af[reg] = sc; Bf[reg] = (b_ff[o] - m_ff[o]) * sc + be_ff[o];
    sc = g_t[o] * rsqrtf(v_t[o] + EPS_);   At[reg] = sc; Bt[reg] = (b_t[o] - m_t[o]) * sc + be_t[o];
  }

  const int q1 = quad & 1;
  const int qp = (2 * w + (quad >> 1)) & 3;
  const int kfp = w >> 1;
  f32x4 y4res[4][2];  // center-slice residuals (f32)
#pragma unroll
  for (int tl = 0; tl < 6; ++tl) {
    int t = t0 - 1 + tl;
    if (t >= 0 && t < 400) {
#pragma unroll
      for (int vt = 0; vt < 2; ++vt) {
        int v = vt * 16 + m;
        unsigned p = (unsigned)(n * 10800 + t * 27 + v);  // v>=27 spill benign
        f32x4 acc = z4();
#pragma unroll
        for (int kf = 0; kf < 2; ++kf) {
          short8 b = *(const short8*)&y3T[p * 64 + kf * 32 + quad * 8];
          acc = MFMA(aWf[kf], b, acc);
        }
        s4v pk;
        f32x4 yr;
#pragma unroll
        for (int reg = 0; reg < 4; ++reg) {
          int o = 16 * w + quad * 4 + reg;
          float xr = (v < 27) ? x[((n * 64 + o) * 400 + t) * 27 + v] : 0.f;
          float r = xr + acc[reg] * Af[reg] + Bf[reg];
          r = (r >= 0.f) ? r : LEAK * r;
          yr[reg] = r;
          pk[reg] = (short)f2u(r);
        }
        if (tl >= 1 && tl <= 4) y4res[tl - 1][vt] = yr;
        *(s4v*)((u16*)&sy4f[tl][vt][kfp][qp * 16 + m] + 4 * q1) = pk;
      }
    } else {
      s4v zz = {0, 0, 0, 0};
#pragma unroll
      for (int vt = 0; vt < 2; ++vt) {
        if (tl >= 1 && tl <= 4) y4res[tl - 1][vt] = z4();
        *(s4v*)((u16*)&sy4f[tl][vt][kfp][qp * 16 + m] + 4 * q1) = zz;
      }
    }
  }
  __syncthreads();
#pragma unroll
  for (int tc = 0; tc < 4; ++tc) {
    int t = t0 + tc;
#pragma unroll
    for (int vt = 0; vt < 2; ++vt) {
      f32x4 acc = z4();
#pragma unroll
      for (int kf = 0; kf < 6; ++kf) {
        short8 b = *(const short8*)&sy4f[tc + (kf >> 1)][vt][kf & 1][lane];
        acc = MFMA(aWt[kf], b, acc);
      }
      int v = vt * 16 + m;
      if (v < 27) {
#pragma unroll
        for (int reg = 0; reg < 4; ++reg) {
          int o = 16 * w + quad * 4 + reg;
          float r = y4res[tc][vt][reg] + acc[reg] * At[reg] + Bt[reg];
          out[((n * 64 + o) * 400 + t) * 27 + v] = (r >= 0.f) ? r : LEAK * r;
        }
      }
    }
  }
}

// ---------------------------------------------------------------------------
extern "C" void kernel_launch(void* const* d_in, const int* in_sizes, int n_in,
                              void* d_out, int out_size, void* d_ws, size_t ws_size,
                              hipStream_t stream)
{
  const float* x      = (const float*)d_in[0];
  const float* pe     = (const float*)d_in[1];
  const float* W_in   = (const float*)d_in[2];
  const float* b_in   = (const float*)d_in[3];
  const float* alphas = (const float*)d_in[4];
  const float* att0   = (const float*)d_in[5];
  const float* W_out  = (const float*)d_in[6];
  const float* b_out  = (const float*)d_in[7];
  const float* g_out  = (const float*)d_in[8];
  const float* be_out = (const float*)d_in[9];
  const float* m_out  = (const float*)d_in[10];
  const float* v_out  = (const float*)d_in[11];
  const float* W_ff   = (const float*)d_in[12];
  const float* b_ff   = (const float*)d_in[13];
  const float* g_ff   = (const float*)d_in[14];
  const float* be_ff  = (const float*)d_in[15];
  const float* m_ff   = (const float*)d_in[16];
  const float* v_ff   = (const float*)d_in[17];
  const float* W_t    = (const float*)d_in[18];
  const float* b_t    = (const float*)d_in[19];
  const float* g_t    = (const float*)d_in[20];
  const float* be_t   = (const float*)d_in[21];
  const float* m_t    = (const float*)d_in[22];
  const float* v_t    = (const float*)d_in[23];

  // workspace layout (needs ~53.5 MB):
  //   [0, 746496)                     att f32 [32][2][27][27]
  //   [1MB, 1MB+26.2MB)               qG bf16 [32][2][32u][6400]
  //   [1MB+26.2MB, 1MB+52.4MB)        kG bf16 (same shape)
  //   [1MB, 1MB+44.2MB)               y3T bf16 [345600][64]  (aliases qG/kG,
  //                                   written only after g_att completes)
  float* att = (float*)d_ws;
  u16* qG  = (u16*)((char*)d_ws + (1u << 20));
  u16* kG  = (u16*)((char*)d_ws + (1u << 20) + 26214400u);
  u16* y3T = (u16*)((char*)d_ws + (1u << 20));

  g_qk<<<dim3(43, 32), 256, 0, stream>>>(x, pe, W_in, b_in, qG, kG);
  g_att<<<dim3(2, 32), 256, 0, stream>>>(qG, kG, alphas, att0, att);
  g_ab<<<dim3(100, 32), 256, 0, stream>>>(
      x, att, W_out, b_out, g_out, be_out, m_out, v_out, y3T);
  g_cd<<<dim3(100, 32), 256, 0, stream>>>(
      x, y3T, W_ff, b_ff, g_ff, be_ff, m_ff, v_ff,
      W_t, b_t, g_t, be_t, m_t, v_t, (float*)d_out);
}

// Round 5
// 429.569 us; speedup vs baseline: 1.0769x; 1.0769x over previous
//
#include <hip/hip_runtime.h>
#include <hip/hip_bf16.h>

typedef __hip_bfloat16 bf16;
typedef unsigned short u16;
typedef __attribute__((ext_vector_type(8))) short short8;
typedef __attribute__((ext_vector_type(4))) short s4v;
typedef __attribute__((ext_vector_type(4))) float f32x4;
typedef __attribute__((ext_vector_type(4))) unsigned int u32x4;

#define LEAK 0.1f
#define EPS_ 1e-5f
#define MFMA(a, b, c) __builtin_amdgcn_mfma_f32_16x16x32_bf16(a, b, c, 0, 0, 0)
// N=32 C=64 T=400 V=27 S=2 IC=16 O=64; P = T*V = 10800 per n.

__device__ __forceinline__ float u2f(u16 u) { return __uint_as_float(((unsigned int)u) << 16); }
__device__ __forceinline__ u16 f2u(float f) {
  bf16 h = __float2bfloat16(f);
  u16 r;
  __builtin_memcpy(&r, &h, 2);
  return r;
}
__device__ __forceinline__ f32x4 z4() { f32x4 z = {0.f, 0.f, 0.f, 0.f}; return z; }

// ---------------------------------------------------------------------------
// G1: qk = W_in @ (x+pe) + b_in over P. 8 waves, 256 p per block.
// wave: ot=w&3 -> row-tile (q s0/s1, k s0/s1); g=w>>2 -> p-tile half.
// Output transposed for logit kernel: qG/kG[n][s][u(pad32)][t*16+i].
// ---------------------------------------------------------------------------
__global__ __launch_bounds__(512, 4) void g_qk(
    const float* __restrict__ x, const float* __restrict__ pe,
    const float* __restrict__ W_in, const float* __restrict__ b_in,
    u16* __restrict__ qG, u16* __restrict__ kG)
{
  __shared__ u32x4 sB[16][2][64];  // [p-tile][kf][lane] pre-fragmented B (32 KB)
  const int tid = threadIdx.x;
  const int w = tid >> 6, lane = tid & 63;
  const int m = lane & 15, quad = lane >> 4;
  const int ot = w & 3, g = w >> 2;
  const int n = blockIdx.y, p0 = blockIdx.x * 256;

  // persistent W_in A-frags (rows r = 16*ot+m)  [verified pattern]
  short8 aW[2];
#pragma unroll
  for (int kf = 0; kf < 2; ++kf) {
    short8 tt;
#pragma unroll
    for (int j = 0; j < 8; ++j)
      tt[j] = (short)f2u(W_in[(16 * ot + m) * 64 + 32 * kf + 8 * quad + j]);
    aW[kf] = tt;
  }
  float bb[4];
#pragma unroll
  for (int r = 0; r < 4; ++r) bb[r] = b_in[16 * ot + quad * 4 + r];

  // stage: 2048 slots / 512 threads = 4 each; global reads coalesced along p
#pragma unroll
  for (int k = 0; k < 4; ++k) {
    int slot = tid + 512 * k;
    int tile = slot >> 7, kf = (slot >> 6) & 1;
    int qq = (slot >> 4) & 3, mm = slot & 15;
    int p = p0 + tile * 16 + mm;
    int c0 = kf * 32 + qq * 8;
    short8 tt = {0, 0, 0, 0, 0, 0, 0, 0};
    if (p < 10800) {
#pragma unroll
      for (int j = 0; j < 8; ++j)
        tt[j] = (short)f2u(x[(n * 64 + c0 + j) * 10800 + p] +
                           pe[(c0 + j) * 10800 + p]);
    }
    *(short8*)&sB[tile][kf][slot & 63] = tt;
  }
  __syncthreads();

  u16* dst = (ot < 2 ? qG : kG) + (n * 2 + (ot & 1)) * 32 * 6400;
#pragma unroll 4
  for (int ti = 0; ti < 8; ++ti) {
    int tile = 8 * g + ti;
    short8 b0 = *(const short8*)&sB[tile][0][lane];
    short8 b1 = *(const short8*)&sB[tile][1][lane];
    f32x4 acc = MFMA(aW[0], b0, z4());
    acc = MFMA(aW[1], b1, acc);
    int p = p0 + tile * 16 + m;
    if (p < 10800) {
      unsigned t = (unsigned)p / 27u;
      unsigned u = (unsigned)p - 27u * t;
      s4v pk;
#pragma unroll
      for (int reg = 0; reg < 4; ++reg) pk[reg] = (short)f2u(acc[reg] + bb[reg]);
      *(s4v*)&dst[(u * 400 + t) * 16 + quad * 4] = pk;
    }
  }
}

// ---------------------------------------------------------------------------
// G2a (split-K): partial logit sums. Block = (s*25+kc, n); K-chunk = 256.
// 1600 blocks. LDS reduce across 4 waves, then atomicAdd raw sums to att.
// ---------------------------------------------------------------------------
__global__ __launch_bounds__(256) void g_att_part(
    const u16* __restrict__ qG, const u16* __restrict__ kG,
    float* __restrict__ att)
{
  __shared__ float sred[4][64][16];
  const int tid = threadIdx.x;
  const int w = tid >> 6, lane = tid & 63;
  const int m = lane & 15, quad = lane >> 4;
  const int s = blockIdx.x / 25, kc = blockIdx.x % 25;
  const int n = blockIdx.y;
  const u16* qb = qG + (n * 2 + s) * 32 * 6400;
  const u16* kb = kG + (n * 2 + s) * 32 * 6400;

  f32x4 a00 = z4(), a01 = z4(), a10 = z4(), a11 = z4();
  const int kk0 = kc * 256 + w * 64;
#pragma unroll
  for (int kf = 0; kf < 2; ++kf) {
    int kk = kk0 + kf * 32 + quad * 8;
    short8 aq0 = *(const short8*)&qb[m * 6400 + kk];
    short8 aq1 = *(const short8*)&qb[(16 + m) * 6400 + kk];
    short8 bk0 = *(const short8*)&kb[m * 6400 + kk];
    short8 bk1 = *(const short8*)&kb[(16 + m) * 6400 + kk];
    a00 = MFMA(aq0, bk0, a00);
    a01 = MFMA(aq0, bk1, a01);
    a10 = MFMA(aq1, bk0, a10);
    a11 = MFMA(aq1, bk1, a11);
  }
  *(f32x4*)&sred[w][lane][0] = a00;
  *(f32x4*)&sred[w][lane][4] = a01;
  *(f32x4*)&sred[w][lane][8] = a10;
  *(f32x4*)&sred[w][lane][12] = a11;
  __syncthreads();
#pragma unroll
  for (int k = 0; k < 4; ++k) {
    int slot = tid + 256 * k;
    int lsrc = slot >> 4, idx = slot & 15;
    float val = sred[0][lsrc][idx] + sred[1][lsrc][idx] +
                sred[2][lsrc][idx] + sred[3][lsrc][idx];
    int f = idx >> 2, reg = idx & 3;
    int ut = f >> 1, vt = f & 1;
    int qq = lsrc >> 4, mm = lsrc & 15;
    int u = ut * 16 + qq * 4 + reg, v = vt * 16 + mm;
    if (u < 27 && v < 27)
      atomicAdd(&att[(n * 2 + s) * 729 + u * 27 + v], val);
  }
}

// ---------------------------------------------------------------------------
// G2b: att = tanh(acc/6400)*alphas[s] + att0[s,u,v]   (in place)
// ---------------------------------------------------------------------------
__global__ __launch_bounds__(256) void k_att_fin(
    float* __restrict__ att, const float* __restrict__ alphas,
    const float* __restrict__ att0)
{
  int i = blockIdx.x * 256 + threadIdx.x;
  if (i >= 32 * 2 * 729) return;
  int s = (i / 729) & 1;
  int r = i % 729;
  att[i] = tanhf(att[i] * (1.f / 6400.f)) * alphas[s] + att0[s * 729 + r];
}

// ---------------------------------------------------------------------------
// G3 (y2+y3 fused): 8 waves, 4 t per block. ot=w&3 -> o-rows; g=w>>2 -> t
// parity. Phase1: y2 frags -> LDS (half-slot b64). ONE barrier.
// Phase2: y3 = lrelu(x + bn(W_out@y2)) -> y3T[n*10800+p][o64].
// ---------------------------------------------------------------------------
__global__ __launch_bounds__(512, 4) void g_ab(
    const float* __restrict__ x, const float* __restrict__ att,
    const float* __restrict__ W_out, const float* __restrict__ b_out,
    const float* __restrict__ g_out, const float* __restrict__ be_out,
    const float* __restrict__ m_out, const float* __restrict__ v_out,
    u16* __restrict__ y3T)
{
  __shared__ u32x4 sy2f[4][2][4][64];  // [t][vt][kf][lane] (32 KB)
  const int tid = threadIdx.x;
  const int w = tid >> 6, lane = tid & 63;
  const int m = lane & 15, quad = lane >> 4;
  const int ot = w & 3, g = w >> 2;
  const int n = blockIdx.y, t0 = blockIdx.x * 4;

  // att B-frags (same for all waves)  [verified pattern]
  short8 bAtt[4];
#pragma unroll
  for (int s = 0; s < 2; ++s)
#pragma unroll
    for (int nt = 0; nt < 2; ++nt) {
      short8 tt;
#pragma unroll
      for (int j = 0; j < 8; ++j) {
        int u = 8 * quad + j, v = 16 * nt + m;
        tt[j] = (u < 27 && v < 27) ? (short)f2u(att[(n * 2 + s) * 729 + u * 27 + v]) : (short)0;
      }
      bAtt[s * 2 + nt] = tt;
    }
  // W_out A-frags + BN consts for rows 16*ot  [verified patterns]
  short8 aWo[4];
#pragma unroll
  for (int kf = 0; kf < 4; ++kf) {
    short8 tt;
#pragma unroll
    for (int j = 0; j < 8; ++j)
      tt[j] = (short)f2u(W_out[(16 * ot + m) * 128 + 32 * kf + 8 * quad + j]);
    aWo[kf] = tt;
  }
  float Ao[4], Bo[4];
#pragma unroll
  for (int reg = 0; reg < 4; ++reg) {
    int o = 16 * ot + quad * 4 + reg;
    float sc = g_out[o] * rsqrtf(v_out[o] + EPS_);
    Ao[reg] = sc;
    Bo[reg] = (b_out[o] - m_out[o]) * sc + be_out[o];
  }

  const int q1 = quad & 1;
  const int qp = (2 * ot + (quad >> 1)) & 3;
  // phase 1: y2 frags; group g handles tc = g, g+2
#pragma unroll
  for (int li = 0; li < 2; ++li) {
    int tc = 2 * li + g;
    int t = t0 + tc;
    short8 ax;
#pragma unroll
    for (int j = 0; j < 8; ++j) {
      int u = quad * 8 + j;
      ax[j] = (u < 27) ? (short)f2u(x[((n * 64 + 16 * ot + m) * 400 + t) * 27 + u]) : (short)0;
    }
    f32x4 acc[4];
#pragma unroll
    for (int f = 0; f < 4; ++f) acc[f] = MFMA(ax, bAtt[f], z4());
#pragma unroll
    for (int s = 0; s < 2; ++s)
#pragma unroll
      for (int nt = 0; nt < 2; ++nt) {
        f32x4 a = acc[s * 2 + nt];
        s4v pk;
#pragma unroll
        for (int reg = 0; reg < 4; ++reg) pk[reg] = (short)f2u(a[reg]);
        int kfp = 2 * s + (ot >> 1);
        *(s4v*)((u16*)&sy2f[tc][nt][kfp][qp * 16 + m] + 4 * q1) = pk;
      }
  }
  __syncthreads();
  // phase 2: y3; group g handles tc = g, g+2
#pragma unroll
  for (int ci = 0; ci < 2; ++ci) {
    int tc = 2 * ci + g;
    int t = t0 + tc;
#pragma unroll
    for (int vt = 0; vt < 2; ++vt) {
      f32x4 a0 = z4();
#pragma unroll
      for (int kf = 0; kf < 4; ++kf) {
        short8 b = *(const short8*)&sy2f[tc][vt][kf][lane];
        a0 = MFMA(aWo[kf], b, a0);
      }
      int v = vt * 16 + m;
      if (v < 27) {
        s4v pk;
#pragma unroll
        for (int reg = 0; reg < 4; ++reg) {
          int o = 16 * ot + quad * 4 + reg;
          float r = x[((n * 64 + o) * 400 + t) * 27 + v] + a0[reg] * Ao[reg] + Bo[reg];
          pk[reg] = (short)f2u((r >= 0.f) ? r : LEAK * r);
        }
        *(s4v*)&y3T[(unsigned)(n * 10800 + t * 27 + v) * 64 + 16 * ot + quad * 4] = pk;
      }
    }
  }
}

// ---------------------------------------------------------------------------
// G4 (y4+z fused): 8 waves, 8 center t + halo (10 slices). ot=w&3 -> o-rows;
// g=w>>2 -> slice parity. Phase1: y4 frags -> LDS. ONE barrier.
// Phase2: z = lrelu(y4 + bn(conv3(y4))); residual y4 re-read from the LDS
// half-slot for (o,v) (written pre-barrier), saving 40 VGPRs of y4res.
// ---------------------------------------------------------------------------
__global__ __launch_bounds__(512, 4) void g_cd(
    const float* __restrict__ x, const u16* __restrict__ y3T,
    const float* __restrict__ W_ff, const float* __restrict__ b_ff,
    const float* __restrict__ g_ff, const float* __restrict__ be_ff,
    const float* __restrict__ m_ff, const float* __restrict__ v_ff,
    const float* __restrict__ W_t, const float* __restrict__ b_t,
    const float* __restrict__ g_t, const float* __restrict__ be_t,
    const float* __restrict__ m_t, const float* __restrict__ v_t,
    float* __restrict__ out)
{
  __shared__ u32x4 sy4f[10][2][2][64];  // [tl][vt][ihalf][lane] (40 KB)
  const int tid = threadIdx.x;
  const int w = tid >> 6, lane = tid & 63;
  const int m = lane & 15, quad = lane >> 4;
  const int ot = w & 3, g = w >> 2;
  const int n = blockIdx.y, t0 = blockIdx.x * 8;

  short8 aWf[2], aWt[6];
#pragma unroll
  for (int kf = 0; kf < 2; ++kf) {
    short8 tt;
#pragma unroll
    for (int j = 0; j < 8; ++j)
      tt[j] = (short)f2u(W_ff[(16 * ot + m) * 64 + 32 * kf + 8 * quad + j]);
    aWf[kf] = tt;
  }
#pragma unroll
  for (int kf = 0; kf < 6; ++kf) {  // k = dt*64 + i   [verified pattern]
    short8 tt;
    int dt = kf >> 1;
#pragma unroll
    for (int j = 0; j < 8; ++j) {
      int ii = 32 * (kf & 1) + 8 * quad + j;
      tt[j] = (short)f2u(W_t[((16 * ot + m) * 64 + ii) * 3 + dt]);
    }
    aWt[kf] = tt;
  }
  float Af[4], Bf[4], At[4], Bt[4];
#pragma unroll
  for (int reg = 0; reg < 4; ++reg) {
    int o = 16 * ot + quad * 4 + reg;
    float sc;
    sc = g_ff[o] * rsqrtf(v_ff[o] + EPS_); Af[reg] = sc; Bf[reg] = (b_ff[o] - m_ff[o]) * sc + be_ff[o];
    sc = g_t[o] * rsqrtf(v_t[o] + EPS_);   At[reg] = sc; Bt[reg] = (b_t[o] - m_t[o]) * sc + be_t[o];
  }

  const int q1 = quad & 1;
  const int qp = (2 * ot + (quad >> 1)) & 3;
  const int kfp = ot >> 1;
  // phase 1: y4 frags; group g handles tl = g, g+2, ..., g+8 (5 each)
#pragma unroll
  for (int li = 0; li < 5; ++li) {
    int tl = 2 * li + g;
    int t = t0 - 1 + tl;
    if (t >= 0 && t < 400) {
#pragma unroll
      for (int vt = 0; vt < 2; ++vt) {
        int v = vt * 16 + m;
        unsigned p = (unsigned)(n * 10800 + t * 27 + v);  // v>=27 spill benign
        f32x4 acc = z4();
#pragma unroll
        for (int kf = 0; kf < 2; ++kf) {
          short8 b = *(const short8*)&y3T[p * 64 + kf * 32 + quad * 8];
          acc = MFMA(aWf[kf], b, acc);
        }
        s4v pk;
#pragma unroll
        for (int reg = 0; reg < 4; ++reg) {
          int o = 16 * ot + quad * 4 + reg;
          float xr = (v < 27) ? x[((n * 64 + o) * 400 + t) * 27 + v] : 0.f;
          float r = xr + acc[reg] * Af[reg] + Bf[reg];
          pk[reg] = (short)f2u((r >= 0.f) ? r : LEAK * r);
        }
        *(s4v*)((u16*)&sy4f[tl][vt][kfp][qp * 16 + m] + 4 * q1) = pk;
      }
    } else {
      s4v zz = {0, 0, 0, 0};
#pragma unroll
      for (int vt = 0; vt < 2; ++vt)
        *(s4v*)((u16*)&sy4f[tl][vt][kfp][qp * 16 + m] + 4 * q1) = zz;
    }
  }
  __syncthreads();
  // phase 2: conv + residual; group g handles tc = g, g+2, g+4, g+6
#pragma unroll
  for (int ci = 0; ci < 4; ++ci) {
    int tc = 2 * ci + g;
    int t = t0 + tc;
#pragma unroll
    for (int vt = 0; vt < 2; ++vt) {
      f32x4 acc = z4();
#pragma unroll
      for (int kf = 0; kf < 6; ++kf) {
        short8 b = *(const short8*)&sy4f[tc + (kf >> 1)][vt][kf & 1][lane];
        acc = MFMA(aWt[kf], b, acc);
      }
      int v = vt * 16 + m;
      if (v < 27) {
        // residual y4[o][v][tl=tc+1]: same (ot,quad,m) half-slot indexing
        s4v res = *(const s4v*)((const u16*)&sy4f[tc + 1][vt][kfp][qp * 16 + m] + 4 * q1);
#pragma unroll
        for (int reg = 0; reg < 4; ++reg) {
          int o = 16 * ot + quad * 4 + reg;
          float r = u2f((u16)res[reg]) + acc[reg] * At[reg] + Bt[reg];
          out[((n * 64 + o) * 400 + t) * 27 + v] = (r >= 0.f) ? r : LEAK * r;
        }
      }
    }
  }
}

// ---------------------------------------------------------------------------
extern "C" void kernel_launch(void* const* d_in, const int* in_sizes, int n_in,
                              void* d_out, int out_size, void* d_ws, size_t ws_size,
                              hipStream_t stream)
{
  const float* x      = (const float*)d_in[0];
  const float* pe     = (const float*)d_in[1];
  const float* W_in   = (const float*)d_in[2];
  const float* b_in   = (const float*)d_in[3];
  const float* alphas = (const float*)d_in[4];
  const float* att0   = (const float*)d_in[5];
  const float* W_out  = (const float*)d_in[6];
  const float* b_out  = (const float*)d_in[7];
  const float* g_out  = (const float*)d_in[8];
  const float* be_out = (const float*)d_in[9];
  const float* m_out  = (const float*)d_in[10];
  const float* v_out  = (const float*)d_in[11];
  const float* W_ff   = (const float*)d_in[12];
  const float* b_ff   = (const float*)d_in[13];
  const float* g_ff   = (const float*)d_in[14];
  const float* be_ff  = (const float*)d_in[15];
  const float* m_ff   = (const float*)d_in[16];
  const float* v_ff   = (const float*)d_in[17];
  const float* W_t    = (const float*)d_in[18];
  const float* b_t    = (const float*)d_in[19];
  const float* g_t    = (const float*)d_in[20];
  const float* be_t   = (const float*)d_in[21];
  const float* m_t    = (const float*)d_in[22];
  const float* v_t    = (const float*)d_in[23];

  // workspace layout (within the 53.5 MB proven-safe footprint):
  //   [0, 186624)                 att f32 [32][2][27][27] (raw sums -> final)
  //   [1MB, 1MB+26.2MB)           qG bf16 [32][2][32u][6400]
  //   [1MB+26.2MB, 1MB+52.4MB)    kG bf16 (same shape)
  //   [1MB, 1MB+44.2MB)           y3T bf16 [345600][64] (aliases qG/kG;
  //                               written only after g_att_part completes)
  float* att = (float*)d_ws;
  u16* qG  = (u16*)((char*)d_ws + (1u << 20));
  u16* kG  = (u16*)((char*)d_ws + (1u << 20) + 26214400u);
  u16* y3T = (u16*)((char*)d_ws + (1u << 20));

  hipMemsetAsync(att, 0, 32 * 2 * 729 * sizeof(float), stream);
  g_qk<<<dim3(43, 32), 512, 0, stream>>>(x, pe, W_in, b_in, qG, kG);
  g_att_part<<<dim3(50, 32), 256, 0, stream>>>(qG, kG, att);
  k_att_fin<<<dim3(183), 256, 0, stream>>>(att, alphas, att0);
  g_ab<<<dim3(100, 32), 512, 0, stream>>>(
      x, att, W_out, b_out, g_out, be_out, m_out, v_out, y3T);
  g_cd<<<dim3(50, 32), 512, 0, stream>>>(
      x, y3T, W_ff, b_ff, g_ff, be_ff, m_ff, v_ff,
      W_t, b_t, g_t, be_t, m_t, v_t, (float*)d_out);
}

// Round 7
// 418.255 us; speedup vs baseline: 1.1061x; 1.0271x over previous
//
#include <hip/hip_runtime.h>
#include <hip/hip_bf16.h>

typedef __hip_bfloat16 bf16;
typedef unsigned short u16;
typedef __attribute__((ext_vector_type(8))) short short8;
typedef __attribute__((ext_vector_type(4))) short s4v;
typedef __attribute__((ext_vector_type(4))) float f32x4;
typedef __attribute__((ext_vector_type(4))) unsigned int u32x4;

#define LEAK 0.1f
#define EPS_ 1e-5f
#define MFMA(a, b, c) __builtin_amdgcn_mfma_f32_16x16x32_bf16(a, b, c, 0, 0, 0)
// N=32 C=64 T=400 V=27 S=2 IC=16 O=64; P = T*V = 10800 per n.

__device__ __forceinline__ float u2f(u16 u) { return __uint_as_float(((unsigned int)u) << 16); }
__device__ __forceinline__ u16 f2u(float f) {
  bf16 h = __float2bfloat16(f);
  u16 r;
  __builtin_memcpy(&r, &h, 2);
  return r;
}
__device__ __forceinline__ f32x4 z4() { f32x4 z = {0.f, 0.f, 0.f, 0.f}; return z; }

// ---------------------------------------------------------------------------
// G1: qk = W_in @ (x+pe) + b_in over P. 8 waves, 256 p per block.
// Staging remapped for MLP: thread = (1 channel, 8 consecutive p) -> two
// f32x4 vector loads from x and pe (half-wave reads 1KB contiguous), then
// 8 ds_write_b16 into the same pre-frag layout. VGPR budget 128 (512,2).
// Output transposed for logit kernel: qG/kG[n][s][u(pad32)][t*16+i].
// ---------------------------------------------------------------------------
__global__ __launch_bounds__(512, 2) void g_qk(
    const float* __restrict__ x, const float* __restrict__ pe,
    const float* __restrict__ W_in, const float* __restrict__ b_in,
    u16* __restrict__ qG, u16* __restrict__ kG)
{
  __shared__ __align__(16) u16 sB16[16 * 2 * 64 * 8];  // [tile][kf][lane][j] (32 KB)
  const int tid = threadIdx.x;
  const int w = tid >> 6, lane = tid & 63;
  const int m = lane & 15, quad = lane >> 4;
  const int ot = w & 3, g = w >> 2;
  const int n = blockIdx.y, p0 = blockIdx.x * 256;

  // persistent W_in A-frags (rows r = 16*ot+m)  [verified pattern]
  short8 aW[2];
#pragma unroll
  for (int kf = 0; kf < 2; ++kf) {
    short8 tt;
#pragma unroll
    for (int j = 0; j < 8; ++j)
      tt[j] = (short)f2u(W_in[(16 * ot + m) * 64 + 32 * kf + 8 * quad + j]);
    aW[kf] = tt;
  }
  float bb[4];
#pragma unroll
  for (int r = 0; r < 4; ++r) bb[r] = b_in[16 * ot + quad * 4 + r];

  // stage: 2048 units of (c, 8p); unit = i*512+tid; c=unit>>5, poct=unit&31
#pragma unroll
  for (int i = 0; i < 4; ++i) {
    int unit = i * 512 + tid;
    int c = unit >> 5, poct = unit & 31;
    int p = p0 + poct * 8;
    const float* xp = &x[(n * 64 + c) * 10800 + p];
    const float* pp = &pe[c * 10800 + p];
    float xv[8];
    if (p + 7 < 10800) {
      *(f32x4*)&xv[0] = *(const f32x4*)xp;       // 16B-aligned: stride 10800*4,
      *(f32x4*)&xv[4] = *(const f32x4*)(xp + 4); // p multiple of 8
      f32x4 pv0 = *(const f32x4*)pp;
      f32x4 pv1 = *(const f32x4*)(pp + 4);
#pragma unroll
      for (int e = 0; e < 4; ++e) { xv[e] += pv0[e]; xv[4 + e] += pv1[e]; }
    } else {
#pragma unroll
      for (int e = 0; e < 8; ++e)
        xv[e] = (p + e < 10800) ? xp[e] + pp[e] : 0.f;
    }
    int kf = c >> 5, qq = (c >> 3) & 3, j = c & 7;
#pragma unroll
    for (int e = 0; e < 8; ++e) {
      int pl = poct * 8 + e;
      int tile = pl >> 4, mm = pl & 15;
      sB16[(((tile * 2 + kf) * 64) + qq * 16 + mm) * 8 + j] = f2u(xv[e]);
    }
  }
  __syncthreads();

  u16* dst = (ot < 2 ? qG : kG) + (n * 2 + (ot & 1)) * 32 * 6400;
#pragma unroll 4
  for (int ti = 0; ti < 8; ++ti) {
    int tile = 8 * g + ti;
    short8 b0 = *(const short8*)&sB16[((tile * 2 + 0) * 64 + lane) * 8];
    short8 b1 = *(const short8*)&sB16[((tile * 2 + 1) * 64 + lane) * 8];
    f32x4 acc = MFMA(aW[0], b0, z4());
    acc = MFMA(aW[1], b1, acc);
    int p = p0 + tile * 16 + m;
    if (p < 10800) {
      unsigned t = (unsigned)p / 27u;
      unsigned u = (unsigned)p - 27u * t;
      s4v pk;
#pragma unroll
      for (int reg = 0; reg < 4; ++reg) pk[reg] = (short)f2u(acc[reg] + bb[reg]);
      *(s4v*)&dst[(u * 400 + t) * 16 + quad * 4] = pk;
    }
  }
}

// ---------------------------------------------------------------------------
// G2a (split-K): partial logit sums. Block = (s*25+kc, n); K-chunk = 256.
// 1600 blocks. LDS reduce across 4 waves, then atomicAdd raw sums to att.
// ---------------------------------------------------------------------------
__global__ __launch_bounds__(256) void g_att_part(
    const u16* __restrict__ qG, const u16* __restrict__ kG,
    float* __restrict__ att)
{
  __shared__ float sred[4][64][16];
  const int tid = threadIdx.x;
  const int w = tid >> 6, lane = tid & 63;
  const int m = lane & 15, quad = lane >> 4;
  const int s = blockIdx.x / 25, kc = blockIdx.x % 25;
  const int n = blockIdx.y;
  const u16* qb = qG + (n * 2 + s) * 32 * 6400;
  const u16* kb = kG + (n * 2 + s) * 32 * 6400;

  f32x4 a00 = z4(), a01 = z4(), a10 = z4(), a11 = z4();
  const int kk0 = kc * 256 + w * 64;
#pragma unroll
  for (int kf = 0; kf < 2; ++kf) {
    int kk = kk0 + kf * 32 + quad * 8;
    short8 aq0 = *(const short8*)&qb[m * 6400 + kk];
    short8 aq1 = *(const short8*)&qb[(16 + m) * 6400 + kk];
    short8 bk0 = *(const short8*)&kb[m * 6400 + kk];
    short8 bk1 = *(const short8*)&kb[(16 + m) * 6400 + kk];
    a00 = MFMA(aq0, bk0, a00);
    a01 = MFMA(aq0, bk1, a01);
    a10 = MFMA(aq1, bk0, a10);
    a11 = MFMA(aq1, bk1, a11);
  }
  *(f32x4*)&sred[w][lane][0] = a00;
  *(f32x4*)&sred[w][lane][4] = a01;
  *(f32x4*)&sred[w][lane][8] = a10;
  *(f32x4*)&sred[w][lane][12] = a11;
  __syncthreads();
#pragma unroll
  for (int k = 0; k < 4; ++k) {
    int slot = tid + 256 * k;
    int lsrc = slot >> 4, idx = slot & 15;
    float val = sred[0][lsrc][idx] + sred[1][lsrc][idx] +
                sred[2][lsrc][idx] + sred[3][lsrc][idx];
    int f = idx >> 2, reg = idx & 3;
    int ut = f >> 1, vt = f & 1;
    int qq = lsrc >> 4, mm = lsrc & 15;
    int u = ut * 16 + qq * 4 + reg, v = vt * 16 + mm;
    if (u < 27 && v < 27)
      atomicAdd(&att[(n * 2 + s) * 729 + u * 27 + v], val);
  }
}

// ---------------------------------------------------------------------------
// G2b: att = tanh(acc/6400)*alphas[s] + att0[s,u,v]   (in place)
// ---------------------------------------------------------------------------
__global__ __launch_bounds__(256) void k_att_fin(
    float* __restrict__ att, const float* __restrict__ alphas,
    const float* __restrict__ att0)
{
  int i = blockIdx.x * 256 + threadIdx.x;
  if (i >= 32 * 2 * 729) return;
  int s = (i / 729) & 1;
  int r = i % 729;
  att[i] = tanhf(att[i] * (1.f / 6400.f)) * alphas[s] + att0[s * 729 + r];
}

// ---------------------------------------------------------------------------
// G3 (y2+y3 fused): 8 waves, 4 t per block. ot=w&3 -> o-rows; g=w>>2 -> t
// parity. MLP: all phase-1 ax loads AND all phase-2 residual x loads are
// issued up front (32 independent loads in flight). VGPR budget 128.
// ---------------------------------------------------------------------------
__global__ __launch_bounds__(512, 2) void g_ab(
    const float* __restrict__ x, const float* __restrict__ att,
    const float* __restrict__ W_out, const float* __restrict__ b_out,
    const float* __restrict__ g_out, const float* __restrict__ be_out,
    const float* __restrict__ m_out, const float* __restrict__ v_out,
    u16* __restrict__ y3T)
{
  __shared__ u32x4 sy2f[4][2][4][64];  // [t][vt][kf][lane] (32 KB)
  const int tid = threadIdx.x;
  const int w = tid >> 6, lane = tid & 63;
  const int m = lane & 15, quad = lane >> 4;
  const int ot = w & 3, g = w >> 2;
  const int n = blockIdx.y, t0 = blockIdx.x * 4;

  // hoisted loads: ax raw (phase 1) + residual x (phase 2)
  float axr[2][8];
#pragma unroll
  for (int li = 0; li < 2; ++li) {
    int t = t0 + 2 * li + g;
    const float* xp = &x[((n * 64 + 16 * ot + m) * 400 + t) * 27];
#pragma unroll
    for (int j = 0; j < 8; ++j) {
      int u = quad * 8 + j;
      axr[li][j] = (u < 27) ? xp[u] : 0.f;
    }
  }
  float xres[2][2][4];
#pragma unroll
  for (int ci = 0; ci < 2; ++ci) {
    int t = t0 + 2 * ci + g;
#pragma unroll
    for (int vt = 0; vt < 2; ++vt) {
      int v = vt * 16 + m;
#pragma unroll
      for (int reg = 0; reg < 4; ++reg) {
        int o = 16 * ot + quad * 4 + reg;
        xres[ci][vt][reg] = (v < 27) ? x[((n * 64 + o) * 400 + t) * 27 + v] : 0.f;
      }
    }
  }

  // att B-frags (same for all waves)  [verified pattern]
  short8 bAtt[4];
#pragma unroll
  for (int s = 0; s < 2; ++s)
#pragma unroll
    for (int nt = 0; nt < 2; ++nt) {
      short8 tt;
#pragma unroll
      for (int j = 0; j < 8; ++j) {
        int u = 8 * quad + j, v = 16 * nt + m;
        tt[j] = (u < 27 && v < 27) ? (short)f2u(att[(n * 2 + s) * 729 + u * 27 + v]) : (short)0;
      }
      bAtt[s * 2 + nt] = tt;
    }
  // W_out A-frags + BN consts for rows 16*ot  [verified patterns]
  short8 aWo[4];
#pragma unroll
  for (int kf = 0; kf < 4; ++kf) {
    short8 tt;
#pragma unroll
    for (int j = 0; j < 8; ++j)
      tt[j] = (short)f2u(W_out[(16 * ot + m) * 128 + 32 * kf + 8 * quad + j]);
    aWo[kf] = tt;
  }
  float Ao[4], Bo[4];
#pragma unroll
  for (int reg = 0; reg < 4; ++reg) {
    int o = 16 * ot + quad * 4 + reg;
    float sc = g_out[o] * rsqrtf(v_out[o] + EPS_);
    Ao[reg] = sc;
    Bo[reg] = (b_out[o] - m_out[o]) * sc + be_out[o];
  }

  const int q1 = quad & 1;
  const int qp = (2 * ot + (quad >> 1)) & 3;
  // phase 1: y2 frags; group g handles tc = g, g+2
#pragma unroll
  for (int li = 0; li < 2; ++li) {
    int tc = 2 * li + g;
    short8 ax;
#pragma unroll
    for (int j = 0; j < 8; ++j) ax[j] = (short)f2u(axr[li][j]);
    f32x4 acc[4];
#pragma unroll
    for (int f = 0; f < 4; ++f) acc[f] = MFMA(ax, bAtt[f], z4());
#pragma unroll
    for (int s = 0; s < 2; ++s)
#pragma unroll
      for (int nt = 0; nt < 2; ++nt) {
        f32x4 a = acc[s * 2 + nt];
        s4v pk;
#pragma unroll
        for (int reg = 0; reg < 4; ++reg) pk[reg] = (short)f2u(a[reg]);
        int kfp = 2 * s + (ot >> 1);
        *(s4v*)((u16*)&sy2f[tc][nt][kfp][qp * 16 + m] + 4 * q1) = pk;
      }
  }
  __syncthreads();
  // phase 2: y3; group g handles tc = g, g+2; residual from xres
#pragma unroll
  for (int ci = 0; ci < 2; ++ci) {
    int tc = 2 * ci + g;
    int t = t0 + tc;
#pragma unroll
    for (int vt = 0; vt < 2; ++vt) {
      f32x4 a0 = z4();
#pragma unroll
      for (int kf = 0; kf < 4; ++kf) {
        short8 b = *(const short8*)&sy2f[tc][vt][kf][lane];
        a0 = MFMA(aWo[kf], b, a0);
      }
      int v = vt * 16 + m;
      if (v < 27) {
        s4v pk;
#pragma unroll
        for (int reg = 0; reg < 4; ++reg) {
          float r = xres[ci][vt][reg] + a0[reg] * Ao[reg] + Bo[reg];
          pk[reg] = (short)f2u((r >= 0.f) ? r : LEAK * r);
        }
        *(s4v*)&y3T[(unsigned)(n * 10800 + t * 27 + v) * 64 + 16 * ot + quad * 4] = pk;
      }
    }
  }
}

// ---------------------------------------------------------------------------
// G4 (y4+z fused): 8 waves, 8 center t + halo (10 slices). ot=w&3 -> o-rows;
// g=w>>2 -> slice parity. MLP: per li, both vt's y3T frags + residual x are
// loaded before any compute. VGPR budget 128. Phase2 unchanged.
// ---------------------------------------------------------------------------
__global__ __launch_bounds__(512, 2) void g_cd(
    const float* __restrict__ x, const u16* __restrict__ y3T,
    const float* __restrict__ W_ff, const float* __restrict__ b_ff,
    const float* __restrict__ g_ff, const float* __restrict__ be_ff,
    const float* __restrict__ m_ff, const float* __restrict__ v_ff,
    const float* __restrict__ W_t, const float* __restrict__ b_t,
    const float* __restrict__ g_t, const float* __restrict__ be_t,
    const float* __restrict__ m_t, const float* __restrict__ v_t,
    float* __restrict__ out)
{
  __shared__ u32x4 sy4f[10][2][2][64];  // [tl][vt][ihalf][lane] (40 KB)
  const int tid = threadIdx.x;
  const int w = tid >> 6, lane = tid & 63;
  const int m = lane & 15, quad = lane >> 4;
  const int ot = w & 3, g = w >> 2;
  const int n = blockIdx.y, t0 = blockIdx.x * 8;

  short8 aWf[2], aWt[6];
#pragma unroll
  for (int kf = 0; kf < 2; ++kf) {
    short8 tt;
#pragma unroll
    for (int j = 0; j < 8; ++j)
      tt[j] = (short)f2u(W_ff[(16 * ot + m) * 64 + 32 * kf + 8 * quad + j]);
    aWf[kf] = tt;
  }
#pragma unroll
  for (int kf = 0; kf < 6; ++kf) {  // k = dt*64 + i   [verified pattern]
    short8 tt;
    int dt = kf >> 1;
#pragma unroll
    for (int j = 0; j < 8; ++j) {
      int ii = 32 * (kf & 1) + 8 * quad + j;
      tt[j] = (short)f2u(W_t[((16 * ot + m) * 64 + ii) * 3 + dt]);
    }
    aWt[kf] = tt;
  }
  float Af[4], Bf[4], At[4], Bt[4];
#pragma unroll
  for (int reg = 0; reg < 4; ++reg) {
    int o = 16 * ot + quad * 4 + reg;
    float sc;
    sc = g_ff[o] * rsqrtf(v_ff[o] + EPS_); Af[reg] = sc; Bf[reg] = (b_ff[o] - m_ff[o]) * sc + be_ff[o];
    sc = g_t[o] * rsqrtf(v_t[o] + EPS_);   At[reg] = sc; Bt[reg] = (b_t[o] - m_t[o]) * sc + be_t[o];
  }

  const int q1 = quad & 1;
  const int qp = (2 * ot + (quad >> 1)) & 3;
  const int kfp = ot >> 1;
  // phase 1: y4 frags; group g handles tl = g, g+2, ..., g+8 (5 each);
  // loads for both vt issued before compute
#pragma unroll
  for (int li = 0; li < 5; ++li) {
    int tl = 2 * li + g;
    int t = t0 - 1 + tl;
    if (t >= 0 && t < 400) {
      short8 yb[2][2];
      float xr[2][4];
#pragma unroll
      for (int vt = 0; vt < 2; ++vt) {
        int v = vt * 16 + m;
        unsigned p = (unsigned)(n * 10800 + t * 27 + v);  // v>=27 spill benign
        yb[vt][0] = *(const short8*)&y3T[p * 64 + quad * 8];
        yb[vt][1] = *(const short8*)&y3T[p * 64 + 32 + quad * 8];
#pragma unroll
        for (int reg = 0; reg < 4; ++reg) {
          int o = 16 * ot + quad * 4 + reg;
          xr[vt][reg] = (v < 27) ? x[((n * 64 + o) * 400 + t) * 27 + v] : 0.f;
        }
      }
#pragma unroll
      for (int vt = 0; vt < 2; ++vt) {
        f32x4 acc = MFMA(aWf[0], yb[vt][0], z4());
        acc = MFMA(aWf[1], yb[vt][1], acc);
        s4v pk;
#pragma unroll
        for (int reg = 0; reg < 4; ++reg) {
          float r = xr[vt][reg] + acc[reg] * Af[reg] + Bf[reg];
          pk[reg] = (short)f2u((r >= 0.f) ? r : LEAK * r);
        }
        *(s4v*)((u16*)&sy4f[tl][vt][kfp][qp * 16 + m] + 4 * q1) = pk;
      }
    } else {
      s4v zz = {0, 0, 0, 0};
#pragma unroll
      for (int vt = 0; vt < 2; ++vt)
        *(s4v*)((u16*)&sy4f[tl][vt][kfp][qp * 16 + m] + 4 * q1) = zz;
    }
  }
  __syncthreads();
  // phase 2: conv + residual; group g handles tc = g, g+2, g+4, g+6
#pragma unroll
  for (int ci = 0; ci < 4; ++ci) {
    int tc = 2 * ci + g;
    int t = t0 + tc;
#pragma unroll
    for (int vt = 0; vt < 2; ++vt) {
      f32x4 acc = z4();
#pragma unroll
      for (int kf = 0; kf < 6; ++kf) {
        short8 b = *(const short8*)&sy4f[tc + (kf >> 1)][vt][kf & 1][lane];
        acc = MFMA(aWt[kf], b, acc);
      }
      int v = vt * 16 + m;
      if (v < 27) {
        // residual y4[o][v][tl=tc+1]: same (ot,quad,m) half-slot indexing
        s4v res = *(const s4v*)((const u16*)&sy4f[tc + 1][vt][kfp][qp * 16 + m] + 4 * q1);
#pragma unroll
        for (int reg = 0; reg < 4; ++reg) {
          int o = 16 * ot + quad * 4 + reg;
          float r = u2f((u16)res[reg]) + acc[reg] * At[reg] + Bt[reg];
          out[((n * 64 + o) * 400 + t) * 27 + v] = (r >= 0.f) ? r : LEAK * r;
        }
      }
    }
  }
}

// ---------------------------------------------------------------------------
extern "C" void kernel_launch(void* const* d_in, const int* in_sizes, int n_in,
                              void* d_out, int out_size, void* d_ws, size_t ws_size,
                              hipStream_t stream)
{
  const float* x      = (const float*)d_in[0];
  const float* pe     = (const float*)d_in[1];
  const float* W_in   = (const float*)d_in[2];
  const float* b_in   = (const float*)d_in[3];
  const float* alphas = (const float*)d_in[4];
  const float* att0   = (const float*)d_in[5];
  const float* W_out  = (const float*)d_in[6];
  const float* b_out  = (const float*)d_in[7];
  const float* g_out  = (const float*)d_in[8];
  const float* be_out = (const float*)d_in[9];
  const float* m_out  = (const float*)d_in[10];
  const float* v_out  = (const float*)d_in[11];
  const float* W_ff   = (const float*)d_in[12];
  const float* b_ff   = (const float*)d_in[13];
  const float* g_ff   = (const float*)d_in[14];
  const float* be_ff  = (const float*)d_in[15];
  const float* m_ff   = (const float*)d_in[16];
  const float* v_ff   = (const float*)d_in[17];
  const float* W_t    = (const float*)d_in[18];
  const float* b_t    = (const float*)d_in[19];
  const float* g_t    = (const float*)d_in[20];
  const float* be_t   = (const float*)d_in[21];
  const float* m_t    = (const float*)d_in[22];
  const float* v_t    = (const float*)d_in[23];

  // workspace layout (within the 53.5 MB proven-safe footprint):
  //   [0, 186624)                 att f32 [32][2][27][27] (raw sums -> final)
  //   [1MB, 1MB+26.2MB)           qG bf16 [32][2][32u][6400]
  //   [1MB+26.2MB, 1MB+52.4MB)    kG bf16 (same shape)
  //   [1MB, 1MB+44.2MB)           y3T bf16 [345600][64] (aliases qG/kG;
  //                               written only after g_att_part completes)
  float* att = (float*)d_ws;
  u16* qG  = (u16*)((char*)d_ws + (1u << 20));
  u16* kG  = (u16*)((char*)d_ws + (1u << 20) + 26214400u);
  u16* y3T = (u16*)((char*)d_ws + (1u << 20));

  hipMemsetAsync(att, 0, 32 * 2 * 729 * sizeof(float), stream);
  g_qk<<<dim3(43, 32), 512, 0, stream>>>(x, pe, W_in, b_in, qG, kG);
  g_att_part<<<dim3(50, 32), 256, 0, stream>>>(qG, kG, att);
  k_att_fin<<<dim3(183), 256, 0, stream>>>(att, alphas, att0);
  g_ab<<<dim3(100, 32), 512, 0, stream>>>(
      x, att, W_out, b_out, g_out, be_out, m_out, v_out, y3T);
  g_cd<<<dim3(50, 32), 512, 0, stream>>>(
      x, y3T, W_ff, b_ff, g_ff, be_ff, m_ff, v_ff,
      W_t, b_t, g_t, be_t, m_t, v_t, (float*)d_out);
}